// Round 11
// baseline (6662.075 us; speedup 1.0000x reference)
//
#include <hip/hip_runtime.h>
#include <math.h>

// Model: S=1024, V=32000, H=1024. Attention dead code => context = sum enc_h.
//
// Round-11 structure == round-5 proven serial pipeline, with the fp32 logits
// GEMM + argmax replaced by the round-10 bf16x3 MFMA kernel (only delta):
//   memsets: amax+zerovec zero; enc_out/dec_h NaN sentinel
//   gemm_nt<1>: G_enc = embed[input_seq] @ enc_Wih^T + enc_b
//   lstm_seq  : encoder (round-5 proven body) -> enc_out, c0, ctx
//   ctx_bias_k: ctxb = dec_b + dec_Wih[:,H:] @ ctx
//   gemm_nt<2>: G_dec = relu(prev) @ dec_Wih[:,:H]^T   [right before decoder:
//               G_dec L2/LLC-hot => round-5's 2135us decoder; rounds 9/10
//               measured +600..870us when this GEMM ran at pipeline start]
//   dec_lstm  : decoder (round-5 body + per-thread gctx)
//   logits_mfma: bf16x3 split MFMA GEMM (ah*bh+ah*bl+al*bh, fp32 accum)
//                + bias + store + fused packed-key argmax (atomicMax)
//   idx_final : decode argmax keys -> d_out[S*V..]

#define S_LEN 1024
#define HDIM  1024
#define VDIM  32000

typedef float f4 __attribute__((ext_vector_type(4)));
typedef float f32x4 __attribute__((ext_vector_type(4)));
typedef short short8 __attribute__((ext_vector_type(8)));
typedef short sh4 __attribute__((ext_vector_type(4)));

__device__ __forceinline__ void agent_storef(float* p, float v) {
    __hip_atomic_store(p, v, __ATOMIC_RELAXED, __HIP_MEMORY_SCOPE_AGENT);
}
__device__ __forceinline__ float sigmoidf_(float x) {
    return 1.0f / (1.0f + expf(-x));
}
__device__ __forceinline__ void llc_load_4x4(const float* p, f4& a, f4& b,
                                             f4& c, f4& d) {
    asm volatile(
        "global_load_dwordx4 %0, %4, off sc0 sc1\n\t"
        "global_load_dwordx4 %1, %4, off offset:1024 sc0 sc1\n\t"
        "global_load_dwordx4 %2, %4, off offset:2048 sc0 sc1\n\t"
        "global_load_dwordx4 %3, %4, off offset:3072 sc0 sc1\n\t"
        "s_waitcnt vmcnt(0)"
        : "=&v"(a), "=&v"(b), "=&v"(c), "=&v"(d)
        : "v"(p) : "memory");
}
__device__ __forceinline__ bool any_nan16(f4 a, f4 b, f4 c, f4 d) {
    float s0 = (a.x + a.y) + (a.z + a.w);
    float s1 = (b.x + b.y) + (b.z + b.w);
    float s2 = (c.x + c.y) + (c.z + c.w);
    float s3 = (d.x + d.y) + (d.z + d.w);
    float s  = (s0 + s1) + (s2 + s3);
    return s != s;
}
__device__ __forceinline__ int swz(int s) {
    return (s & ~7) | ((s ^ (s >> 3)) & 7);
}
// RNE split: x = hi + lo with |lo| <= 2^-9 |x|, both bf16.
__device__ __forceinline__ void split_bf16(float x, unsigned short& h,
                                           unsigned short& l) {
    unsigned u = __float_as_uint(x);
    unsigned hr = (u + 0x7FFFu + ((u >> 16) & 1u)) >> 16;
    h = (unsigned short)hr;
    float hf = __uint_as_float(hr << 16);
    float r = x - hf;
    unsigned v = __float_as_uint(r);
    l = (unsigned short)((v + 0x7FFFu + ((v >> 16) & 1u)) >> 16);
}

// ---------------------------------------------------------------------------
// Input GEMMs (round-5 proven kernel): 256 threads, 128x128 tile, BK=16.
// MODE 1: A = embed[gidx[m]], +bias; MODE 2: A = relu(embed[gidx[m-1]]),
// row0 = 0, no bias.
// ---------------------------------------------------------------------------
template<int MODE>
__global__ __launch_bounds__(256)
void gemm_nt(const float* __restrict__ B, int ldb,
             const float* __restrict__ bias,
             float* __restrict__ C, int ldc,
             const float* __restrict__ embed,
             const int* __restrict__ gidx,
             int M, int N, int K)
{
    __shared__ float As[16][128];
    __shared__ float Bs[16][128];

    const int tid = threadIdx.x;
    const int m0 = blockIdx.y * 128;
    const int n0 = blockIdx.x * 128;

    float acc[8][8];
#pragma unroll
    for (int r = 0; r < 8; ++r)
#pragma unroll
        for (int c = 0; c < 8; ++c) acc[r][c] = 0.0f;

    const int ty = tid >> 4;
    const int tx = tid & 15;

    for (int k0 = 0; k0 < K; k0 += 16) {
#pragma unroll
        for (int q = 0; q < 2; ++q) {
            int id = tid * 2 + q;
            int m  = id >> 2;
            int c4 = (id & 3) * 4;
            float4 v;
            if (MODE == 1) {
                int row = gidx[m0 + m];
                v = *(const float4*)(embed + (size_t)row * HDIM + k0 + c4);
            } else {
                int mg = m0 + m;
                if (mg == 0) {
                    v = make_float4(0.f, 0.f, 0.f, 0.f);
                } else {
                    int row = gidx[mg - 1];
                    v = *(const float4*)(embed + (size_t)row * HDIM + k0 + c4);
                    v.x = fmaxf(v.x, 0.f); v.y = fmaxf(v.y, 0.f);
                    v.z = fmaxf(v.z, 0.f); v.w = fmaxf(v.w, 0.f);
                }
            }
            As[c4 + 0][m] = v.x; As[c4 + 1][m] = v.y;
            As[c4 + 2][m] = v.z; As[c4 + 3][m] = v.w;
        }
#pragma unroll
        for (int q = 0; q < 2; ++q) {
            int id = tid * 2 + q;
            int n  = id >> 2;
            int c4 = (id & 3) * 4;
            float4 v = *(const float4*)(B + (size_t)(n0 + n) * ldb + k0 + c4);
            Bs[c4 + 0][n] = v.x; Bs[c4 + 1][n] = v.y;
            Bs[c4 + 2][n] = v.z; Bs[c4 + 3][n] = v.w;
        }
        __syncthreads();

#pragma unroll
        for (int k = 0; k < 16; ++k) {
            float4 a0 = *(const float4*)&As[k][ty * 8];
            float4 a1 = *(const float4*)&As[k][ty * 8 + 4];
            float4 b0 = *(const float4*)&Bs[k][tx * 8];
            float4 b1 = *(const float4*)&Bs[k][tx * 8 + 4];
            float av[8] = {a0.x,a0.y,a0.z,a0.w,a1.x,a1.y,a1.z,a1.w};
            float bv[8] = {b0.x,b0.y,b0.z,b0.w,b1.x,b1.y,b1.z,b1.w};
#pragma unroll
            for (int r = 0; r < 8; ++r)
#pragma unroll
                for (int c = 0; c < 8; ++c)
                    acc[r][c] = fmaf(av[r], bv[c], acc[r][c]);
        }
        __syncthreads();
    }

    const int mbase = m0 + ty * 8;
    const int nbase = n0 + tx * 8;
#pragma unroll
    for (int r = 0; r < 8; ++r) {
        float4 o0, o1;
        float b0 = (MODE == 2) ? 0.f : bias[nbase + 0];
        float b1 = (MODE == 2) ? 0.f : bias[nbase + 1];
        float b2 = (MODE == 2) ? 0.f : bias[nbase + 2];
        float b3 = (MODE == 2) ? 0.f : bias[nbase + 3];
        float b4 = (MODE == 2) ? 0.f : bias[nbase + 4];
        float b5 = (MODE == 2) ? 0.f : bias[nbase + 5];
        float b6 = (MODE == 2) ? 0.f : bias[nbase + 6];
        float b7 = (MODE == 2) ? 0.f : bias[nbase + 7];
        o0.x = acc[r][0] + b0; o0.y = acc[r][1] + b1;
        o0.z = acc[r][2] + b2; o0.w = acc[r][3] + b3;
        o1.x = acc[r][4] + b4; o1.y = acc[r][5] + b5;
        o1.z = acc[r][6] + b6; o1.w = acc[r][7] + b7;
        *(float4*)(C + (size_t)(mbase + r) * ldc + nbase)     = o0;
        *(float4*)(C + (size_t)(mbase + r) * ldc + nbase + 4) = o1;
    }
}

// ---------------------------------------------------------------------------
// LSTM body — round-5 proven step (no prefetch ring; G is L2/LLC-hot given
// the launch ordering). GCTX=0: encoder; GCTX=1: decoder (+gctx per thread).
// ---------------------------------------------------------------------------
template<int GCTX>
__device__ void lstm_body(const float* __restrict__ Whh,
                          const float* __restrict__ G,
                          const float* __restrict__ gctx_vec,
                          const float* __restrict__ h_init,
                          const float* __restrict__ c_init,
                          float* __restrict__ h_out,
                          float* __restrict__ c_fin,
                          float* __restrict__ csum_out,
                          int slen)
{
    __shared__ f4 hbuf[256];
    const int tid = threadIdx.x;
    const int g   = blockIdx.x;
    const int wv  = tid >> 6;
    const int lg  = tid & 63;
    const int j   = g * 8 + wv;

    f4 W[4][4];
#pragma unroll
    for (int q = 0; q < 4; ++q)
#pragma unroll
        for (int i = 0; i < 4; ++i)
            W[q][i] = *(const f4*)(Whh + (size_t)(j + q * HDIM) * HDIM
                                   + 4 * lg + 256 * i);

    float c = 0.0f, csum = 0.0f;
    if (lg == 0) c = c_init[j];

    float gctx = 0.0f;
    if (GCTX) gctx = gctx_vec[(size_t)(lg & 3) * HDIM + j];

    float gnow = G[(size_t)(lg & 3) * HDIM + j] + gctx;

    for (int t = 0; t < slen; ++t) {
#pragma unroll
        for (int q = 0; q < 4; ++q)
#pragma unroll
            for (int i = 0; i < 4; ++i)
                asm volatile("" : "+v"(W[q][i]));

        const float* hp = (t == 0) ? h_init : (h_out + (size_t)(t - 1) * HDIM);

        if (wv == 0) {
            f4 a, b, cc, d;
            const float* p = hp + 4 * lg;
            for (;;) {
                llc_load_4x4(p, a, b, cc, d);
                if (!__any(any_nan16(a, b, cc, d))) break;
                __builtin_amdgcn_s_sleep(1);
            }
            hbuf[swz(lg)]       = a;
            hbuf[swz(64 + lg)]  = b;
            hbuf[swz(128 + lg)] = cc;
            hbuf[swz(192 + lg)] = d;
        }
        __syncthreads();

        int tn = (t + 1 < slen) ? (t + 1) : t;
        float gnext = G[(size_t)tn * (4 * HDIM) + (lg & 3) * HDIM + j] + gctx;

        f4 h0 = hbuf[swz(lg)];
        f4 h1 = hbuf[swz(64 + lg)];
        f4 h2 = hbuf[swz(128 + lg)];
        f4 h3 = hbuf[swz(192 + lg)];
        float p0 = 0.f, p1 = 0.f, p2 = 0.f, p3 = 0.f;
        f4 hv;
#pragma unroll
        for (int i = 0; i < 4; ++i) {
            hv = (i == 0) ? h0 : (i == 1) ? h1 : (i == 2) ? h2 : h3;
            p0 = fmaf(W[0][i].x, hv.x, fmaf(W[0][i].y, hv.y,
                 fmaf(W[0][i].z, hv.z, fmaf(W[0][i].w, hv.w, p0))));
            p1 = fmaf(W[1][i].x, hv.x, fmaf(W[1][i].y, hv.y,
                 fmaf(W[1][i].z, hv.z, fmaf(W[1][i].w, hv.w, p1))));
            p2 = fmaf(W[2][i].x, hv.x, fmaf(W[2][i].y, hv.y,
                 fmaf(W[2][i].z, hv.z, fmaf(W[2][i].w, hv.w, p2))));
            p3 = fmaf(W[3][i].x, hv.x, fmaf(W[3][i].y, hv.y,
                 fmaf(W[3][i].z, hv.z, fmaf(W[3][i].w, hv.w, p3))));
        }

        float t01 = __shfl_xor((lg & 1) ? p0 : p1, 1);
        float s01 = ((lg & 1) ? p1 : p0) + t01;
        float t23 = __shfl_xor((lg & 1) ? p2 : p3, 1);
        float s23 = ((lg & 1) ? p3 : p2) + t23;
        float tq  = __shfl_xor((lg & 2) ? s01 : s23, 2);
        float s   = ((lg & 2) ? s23 : s01) + tq;
        s += __shfl_xor(s, 4);
        s += __shfl_xor(s, 8);
        s += __shfl_xor(s, 16);
        s += __shfl_xor(s, 32);

        float pre = s + gnow;
        float act = ((lg & 3) == 2) ? tanhf(pre) : sigmoidf_(pre);
        float a1 = __shfl(act, 1);
        float a2 = __shfl(act, 2);
        float a3 = __shfl(act, 3);

        if (lg == 0) {
            c = a1 * c + act * a2;
            float h = a3 * tanhf(c);
            csum += h;
            agent_storef(h_out + (size_t)t * HDIM + j, h);
        }
        gnow = gnext;
        __syncthreads();
    }

    if (lg == 0) {
        if (c_fin)    c_fin[j]    = c;
        if (csum_out) csum_out[j] = csum;
    }
}

__global__ __launch_bounds__(512, 2)
void lstm_seq(const float* __restrict__ Whh, const float* __restrict__ G,
              const float* __restrict__ h_init, const float* __restrict__ c_init,
              float* __restrict__ h_out, float* __restrict__ c_fin,
              float* __restrict__ csum_out, int slen)
{
    lstm_body<0>(Whh, G, nullptr, h_init, c_init, h_out, c_fin, csum_out, slen);
}

__global__ __launch_bounds__(512, 2)
void dec_lstm(const float* __restrict__ Whh, const float* __restrict__ G,
              const float* __restrict__ ctxb, const float* __restrict__ h_init,
              const float* __restrict__ c_init, float* __restrict__ h_out,
              int slen)
{
    lstm_body<1>(Whh, G, ctxb, h_init, c_init, h_out, nullptr, nullptr, slen);
}

// ctx_bias[r] = dec_b[r] + dot(dec_Wih[r, H:2H], context)
__global__ __launch_bounds__(256)
void ctx_bias_k(const float* __restrict__ dec_Wih,
                const float* __restrict__ dec_b,
                const float* __restrict__ ctx,
                float* __restrict__ out)
{
    const int wv = threadIdx.x >> 6;
    const int lane = threadIdx.x & 63;
    const int r = blockIdx.x * 4 + wv;
    const float* wr = dec_Wih + (size_t)r * (2 * HDIM) + HDIM;
    float s = 0.f;
    for (int k = lane; k < HDIM; k += 64) s += wr[k] * ctx[k];
#pragma unroll
    for (int off = 32; off > 0; off >>= 1) s += __shfl_xor(s, off);
    if (lane == 0) out[r] = s + dec_b[r];
}

// ---------------------------------------------------------------------------
// logits_mfma (round-10 v2): C(1024,32000) = dec_h @ out_w^T + out_b,
// bf16x3 split (ah*bh + ah*bl + al*bh, fp32 MFMA accum), fused per-row
// argmax via packed u64 keys + atomicMax.
// Grid (250, 4), 512 threads (8 waves). Tile 256m x 128n, K-chunk 32.
// Wave w: m-block (w>>1)*64, n-block (w&1)*64; 4x4 frags of 16x16x32.
// ---------------------------------------------------------------------------
#define LSTR 40

__global__ __launch_bounds__(512, 1)
void logits_mfma(const float* __restrict__ Amat,   // dec_h (S,H)
                 const float* __restrict__ Bmat,   // out_w (V,H)
                 const float* __restrict__ bias,   // out_b (V)
                 float* __restrict__ C,            // (S,V)
                 unsigned long long* __restrict__ amax)
{
    __shared__ unsigned short Ah[256][LSTR], Al[256][LSTR];
    __shared__ unsigned short Bh[128][LSTR], Bl[128][LSTR];

    const int tid = threadIdx.x;
    const int l   = tid & 63;
    const int w   = tid >> 6;
    const int n0  = blockIdx.x * 128;
    const int m0  = blockIdx.y * 256;
    const int mb  = (w >> 1) * 64;
    const int nb  = (w & 1) * 64;

    f32x4 acc[4][4];
#pragma unroll
    for (int i = 0; i < 4; ++i)
#pragma unroll
        for (int jj = 0; jj < 4; ++jj) acc[i][jj] = (f32x4){0.f, 0.f, 0.f, 0.f};

    for (int k0 = 0; k0 < HDIM; k0 += 32) {
#pragma unroll
        for (int q = 0; q < 4; ++q) {
            int id  = q * 512 + tid;
            int row = id >> 3;
            int kq  = (id & 7) * 4;
            float4 av = *(const float4*)(Amat + (size_t)(m0 + row) * HDIM
                                         + k0 + kq);
            unsigned short h0,h1,h2,h3, l0,l1,l2,l3;
            split_bf16(av.x, h0, l0); split_bf16(av.y, h1, l1);
            split_bf16(av.z, h2, l2); split_bf16(av.w, h3, l3);
            sh4 hi = {(short)h0, (short)h1, (short)h2, (short)h3};
            sh4 lo = {(short)l0, (short)l1, (short)l2, (short)l3};
            *(sh4*)&Ah[row][kq] = hi;
            *(sh4*)&Al[row][kq] = lo;
        }
#pragma unroll
        for (int q = 0; q < 2; ++q) {
            int id  = q * 512 + tid;
            int row = id >> 3;
            int kq  = (id & 7) * 4;
            float4 bv = *(const float4*)(Bmat + (size_t)(n0 + row) * HDIM
                                         + k0 + kq);
            unsigned short h0,h1,h2,h3, l0,l1,l2,l3;
            split_bf16(bv.x, h0, l0); split_bf16(bv.y, h1, l1);
            split_bf16(bv.z, h2, l2); split_bf16(bv.w, h3, l3);
            sh4 hi = {(short)h0, (short)h1, (short)h2, (short)h3};
            sh4 lo = {(short)l0, (short)l1, (short)l2, (short)l3};
            *(sh4*)&Bh[row][kq] = hi;
            *(sh4*)&Bl[row][kq] = lo;
        }
        __syncthreads();

        const int kb = (l >> 4) * 8;
        short8 a_hi[4], a_lo[4], b_hi[4], b_lo[4];
#pragma unroll
        for (int i = 0; i < 4; ++i) {
            int ra = mb + i * 16 + (l & 15);
            int rb = nb + i * 16 + (l & 15);
            a_hi[i] = *(const short8*)&Ah[ra][kb];
            a_lo[i] = *(const short8*)&Al[ra][kb];
            b_hi[i] = *(const short8*)&Bh[rb][kb];
            b_lo[i] = *(const short8*)&Bl[rb][kb];
        }
#pragma unroll
        for (int i = 0; i < 4; ++i)
#pragma unroll
            for (int jj = 0; jj < 4; ++jj) {
                acc[i][jj] = __builtin_amdgcn_mfma_f32_16x16x32_bf16(
                    a_hi[i], b_hi[jj], acc[i][jj], 0, 0, 0);
                acc[i][jj] = __builtin_amdgcn_mfma_f32_16x16x32_bf16(
                    a_hi[i], b_lo[jj], acc[i][jj], 0, 0, 0);
                acc[i][jj] = __builtin_amdgcn_mfma_f32_16x16x32_bf16(
                    a_lo[i], b_hi[jj], acc[i][jj], 0, 0, 0);
            }
        __syncthreads();
    }

    // epilogue: bias, store, fused argmax (packed monotone-float | ~col key)
#pragma unroll
    for (int i = 0; i < 4; ++i) {
        const int mrow = m0 + mb + i * 16 + ((l >> 4) << 2);
        unsigned long long key[4] = {0ull, 0ull, 0ull, 0ull};
#pragma unroll
        for (int jj = 0; jj < 4; ++jj) {
            int n = n0 + nb + jj * 16 + (l & 15);
            float bv = bias[n];
            f32x4 o = acc[i][jj];
#pragma unroll
            for (int r = 0; r < 4; ++r) {
                float val = o[r] + bv;
                C[(size_t)(mrow + r) * VDIM + n] = val;
                unsigned um = __float_as_uint(val);
                um = (um & 0x80000000u) ? ~um : (um | 0x80000000u);
                unsigned long long k2 = ((unsigned long long)um << 32)
                    | (unsigned long long)(0xFFFFFFFFu - (unsigned)n);
                if (k2 > key[r]) key[r] = k2;
            }
        }
#pragma unroll
        for (int r = 0; r < 4; ++r) {
#pragma unroll
            for (int off = 1; off < 16; off <<= 1) {
                unsigned long long other = __shfl_xor(key[r], off);
                if (other > key[r]) key[r] = other;
            }
            if ((l & 15) == 0)
                atomicMax(&amax[mrow + r], key[r]);
        }
    }
}

// decode argmax keys -> float indices
__global__ __launch_bounds__(256)
void idx_final(const unsigned long long* __restrict__ amax,
               float* __restrict__ out_idx)
{
    int i = blockIdx.x * 256 + threadIdx.x;
    if (i < S_LEN) {
        unsigned col = 0xFFFFFFFFu - (unsigned)(amax[i] & 0xFFFFFFFFull);
        out_idx[i] = (float)col;
    }
}

extern "C" void kernel_launch(void* const* d_in, const int* in_sizes, int n_in,
                              void* d_out, int out_size, void* d_ws, size_t ws_size,
                              hipStream_t stream)
{
    (void)in_sizes; (void)n_in; (void)out_size; (void)ws_size;

    const int*   input_seq = (const int*)d_in[0];
    const int*   gold_seq  = (const int*)d_in[1];
    const float* embed     = (const float*)d_in[2];
    const float* enc_Wih   = (const float*)d_in[3];
    const float* enc_Whh   = (const float*)d_in[4];
    const float* enc_b     = (const float*)d_in[5];
    const float* dec_Wih   = (const float*)d_in[6];
    const float* dec_Whh   = (const float*)d_in[7];
    const float* dec_b     = (const float*)d_in[8];
    // d_in[9..14]: attention params — dead code
    const float* out_w     = (const float*)d_in[15];
    const float* out_b     = (const float*)d_in[16];

    float* out = (float*)d_out;
    float* G_enc = out;                 // dead before logits overwrite (serial)
    float* G_dec = out + 4194304;       // dead before logits overwrite (serial)

    // workspace
    char* wsb = (char*)d_ws;
    unsigned long long* amax = (unsigned long long*)wsb;   // 8 KB
    float* zerovec = (float*)(wsb + 8192);                 // 1024 f
    float* c0      = zerovec + 1024;
    float* ctx     = c0 + 1024;
    float* ctxb    = ctx + 1024;                           // 4096 f
    float* enc_out = ctxb + 4096;                          // S*H
    float* dec_h   = enc_out + 1048576;                    // S*H

    hipMemsetAsync(d_ws, 0, 12288, stream);                // amax + zerovec
    hipMemsetAsync(enc_out, 0xFF, (size_t)S_LEN * HDIM * 4, stream);
    hipMemsetAsync(dec_h,   0xFF, (size_t)S_LEN * HDIM * 4, stream);

    // G_enc = embed[input_seq] @ enc_Wih^T + enc_b
    gemm_nt<1><<<dim3(32, 8), 256, 0, stream>>>(
        enc_Wih, HDIM, enc_b, G_enc, 4 * HDIM,
        embed, input_seq, S_LEN, 4 * HDIM, HDIM);

    // encoder
    lstm_seq<<<128, 512, 0, stream>>>(
        enc_Whh, G_enc, zerovec, zerovec, enc_out, c0, ctx, S_LEN);

    // ctxb = dec_b + dec_Wih[:,H:] @ ctx
    ctx_bias_k<<<1024, 256, 0, stream>>>(dec_Wih, dec_b, ctx, ctxb);

    // G_dec = relu(prev) @ dec_Wih[:,:H]^T  — right before decoder (L2-hot)
    gemm_nt<2><<<dim3(32, 8), 256, 0, stream>>>(
        dec_Wih, 2 * HDIM, nullptr, G_dec, 4 * HDIM,
        embed, gold_seq, S_LEN, 4 * HDIM, HDIM);

    // decoder
    dec_lstm<<<128, 512, 0, stream>>>(
        dec_Whh, G_dec, ctxb, enc_out + (size_t)(S_LEN - 1) * HDIM, c0,
        dec_h, S_LEN);

    // logits (bf16x3 MFMA) + fused argmax
    logits_mfma<<<dim3(VDIM / 128, S_LEN / 256), 512, 0, stream>>>(
        dec_h, out_w, out_b, out, amax);

    // idxs -> d_out[S*V : S*V + S)
    idx_final<<<4, 256, 0, stream>>>(amax, out + (size_t)S_LEN * VDIM);
}

// Round 12
// 4715.147 us; speedup vs baseline: 1.4129x; 1.4129x over previous
//
#include <hip/hip_runtime.h>
#include <math.h>

// Model: S=1024, V=32000, H=1024. Attention dead code => context = sum enc_h.
//
// Round-12 = round-5 proven serial pipeline BIT-EXACT (both LSTMs are the
// identical lstm_seq kernel; ctxb folded into G_dec as the GEMM bias so the
// decoder's G access is a bare load whose waitcnt the compiler sinks into
// the next iteration — rounds 9-11 showed the in-kernel "+gctx" add forces
// the waitcnt into the current step and costs ~900us), plus the round-10/11
// proven bf16x3 MFMA logits kernel replacing fp32 logits+argmax:
//   memsets: amax+zerovec zero; enc_out/dec_h NaN sentinel
//   gemm_nt<1>: G_enc = embed[input_seq] @ enc_Wih^T + enc_b
//   lstm_seq  : encoder -> enc_out, c0, ctx
//   ctx_bias_k: ctxb = dec_b + dec_Wih[:,H:] @ ctx
//   gemm_nt<2>: G_dec = relu(prev) @ dec_Wih[:,:H]^T + ctxb   (bias=ctxb!)
//   lstm_seq  : decoder
//   logits_mfma: bf16x3 split MFMA GEMM + bias + fused packed-key argmax
//   idx_final : decode argmax keys -> d_out[S*V..]

#define S_LEN 1024
#define HDIM  1024
#define VDIM  32000

typedef float f4 __attribute__((ext_vector_type(4)));
typedef float f32x4 __attribute__((ext_vector_type(4)));
typedef short short8 __attribute__((ext_vector_type(8)));
typedef short sh4 __attribute__((ext_vector_type(4)));

__device__ __forceinline__ void agent_storef(float* p, float v) {
    __hip_atomic_store(p, v, __ATOMIC_RELAXED, __HIP_MEMORY_SCOPE_AGENT);
}
__device__ __forceinline__ float sigmoidf_(float x) {
    return 1.0f / (1.0f + expf(-x));
}
__device__ __forceinline__ void llc_load_4x4(const float* p, f4& a, f4& b,
                                             f4& c, f4& d) {
    asm volatile(
        "global_load_dwordx4 %0, %4, off sc0 sc1\n\t"
        "global_load_dwordx4 %1, %4, off offset:1024 sc0 sc1\n\t"
        "global_load_dwordx4 %2, %4, off offset:2048 sc0 sc1\n\t"
        "global_load_dwordx4 %3, %4, off offset:3072 sc0 sc1\n\t"
        "s_waitcnt vmcnt(0)"
        : "=&v"(a), "=&v"(b), "=&v"(c), "=&v"(d)
        : "v"(p) : "memory");
}
__device__ __forceinline__ bool any_nan16(f4 a, f4 b, f4 c, f4 d) {
    float s0 = (a.x + a.y) + (a.z + a.w);
    float s1 = (b.x + b.y) + (b.z + b.w);
    float s2 = (c.x + c.y) + (c.z + c.w);
    float s3 = (d.x + d.y) + (d.z + d.w);
    float s  = (s0 + s1) + (s2 + s3);
    return s != s;
}
__device__ __forceinline__ int swz(int s) {
    return (s & ~7) | ((s ^ (s >> 3)) & 7);
}
// RNE split: x = hi + lo with |lo| <= 2^-9 |x|, both bf16.
__device__ __forceinline__ void split_bf16(float x, unsigned short& h,
                                           unsigned short& l) {
    unsigned u = __float_as_uint(x);
    unsigned hr = (u + 0x7FFFu + ((u >> 16) & 1u)) >> 16;
    h = (unsigned short)hr;
    float hf = __uint_as_float(hr << 16);
    float r = x - hf;
    unsigned v = __float_as_uint(r);
    l = (unsigned short)((v + 0x7FFFu + ((v >> 16) & 1u)) >> 16);
}

// ---------------------------------------------------------------------------
// Input GEMMs (round-5 proven kernel, bias added unconditionally):
// 256 threads, 128x128 tile, BK=16.
// MODE 1: A = embed[gidx[m]]; MODE 2: A = relu(embed[gidx[m-1]]), row0 = 0.
// ---------------------------------------------------------------------------
template<int MODE>
__global__ __launch_bounds__(256)
void gemm_nt(const float* __restrict__ B, int ldb,
             const float* __restrict__ bias,
             float* __restrict__ C, int ldc,
             const float* __restrict__ embed,
             const int* __restrict__ gidx,
             int M, int N, int K)
{
    __shared__ float As[16][128];
    __shared__ float Bs[16][128];

    const int tid = threadIdx.x;
    const int m0 = blockIdx.y * 128;
    const int n0 = blockIdx.x * 128;

    float acc[8][8];
#pragma unroll
    for (int r = 0; r < 8; ++r)
#pragma unroll
        for (int c = 0; c < 8; ++c) acc[r][c] = 0.0f;

    const int ty = tid >> 4;
    const int tx = tid & 15;

    for (int k0 = 0; k0 < K; k0 += 16) {
#pragma unroll
        for (int q = 0; q < 2; ++q) {
            int id = tid * 2 + q;
            int m  = id >> 2;
            int c4 = (id & 3) * 4;
            float4 v;
            if (MODE == 1) {
                int row = gidx[m0 + m];
                v = *(const float4*)(embed + (size_t)row * HDIM + k0 + c4);
            } else {
                int mg = m0 + m;
                if (mg == 0) {
                    v = make_float4(0.f, 0.f, 0.f, 0.f);
                } else {
                    int row = gidx[mg - 1];
                    v = *(const float4*)(embed + (size_t)row * HDIM + k0 + c4);
                    v.x = fmaxf(v.x, 0.f); v.y = fmaxf(v.y, 0.f);
                    v.z = fmaxf(v.z, 0.f); v.w = fmaxf(v.w, 0.f);
                }
            }
            As[c4 + 0][m] = v.x; As[c4 + 1][m] = v.y;
            As[c4 + 2][m] = v.z; As[c4 + 3][m] = v.w;
        }
#pragma unroll
        for (int q = 0; q < 2; ++q) {
            int id = tid * 2 + q;
            int n  = id >> 2;
            int c4 = (id & 3) * 4;
            float4 v = *(const float4*)(B + (size_t)(n0 + n) * ldb + k0 + c4);
            Bs[c4 + 0][n] = v.x; Bs[c4 + 1][n] = v.y;
            Bs[c4 + 2][n] = v.z; Bs[c4 + 3][n] = v.w;
        }
        __syncthreads();

#pragma unroll
        for (int k = 0; k < 16; ++k) {
            float4 a0 = *(const float4*)&As[k][ty * 8];
            float4 a1 = *(const float4*)&As[k][ty * 8 + 4];
            float4 b0 = *(const float4*)&Bs[k][tx * 8];
            float4 b1 = *(const float4*)&Bs[k][tx * 8 + 4];
            float av[8] = {a0.x,a0.y,a0.z,a0.w,a1.x,a1.y,a1.z,a1.w};
            float bv[8] = {b0.x,b0.y,b0.z,b0.w,b1.x,b1.y,b1.z,b1.w};
#pragma unroll
            for (int r = 0; r < 8; ++r)
#pragma unroll
                for (int c = 0; c < 8; ++c)
                    acc[r][c] = fmaf(av[r], bv[c], acc[r][c]);
        }
        __syncthreads();
    }

    const int mbase = m0 + ty * 8;
    const int nbase = n0 + tx * 8;
#pragma unroll
    for (int r = 0; r < 8; ++r) {
        float4 o0, o1;
        o0.x = acc[r][0] + bias[nbase + 0];
        o0.y = acc[r][1] + bias[nbase + 1];
        o0.z = acc[r][2] + bias[nbase + 2];
        o0.w = acc[r][3] + bias[nbase + 3];
        o1.x = acc[r][4] + bias[nbase + 4];
        o1.y = acc[r][5] + bias[nbase + 5];
        o1.z = acc[r][6] + bias[nbase + 6];
        o1.w = acc[r][7] + bias[nbase + 7];
        *(float4*)(C + (size_t)(mbase + r) * ldc + nbase)     = o0;
        *(float4*)(C + (size_t)(mbase + r) * ldc + nbase + 4) = o1;
    }
}

// ---------------------------------------------------------------------------
// Persistent sequential LSTM — the round-5 proven kernel, VERBATIM.
// 128 WGs x 512 threads; sentinel-poll sync; bare G loads (waitcnt sinks to
// next iteration). Used for BOTH encoder and decoder.
// ---------------------------------------------------------------------------
__global__ __launch_bounds__(512, 2)
void lstm_seq(const float* __restrict__ Whh,
              const float* __restrict__ G,        // (S, 4H) preactivations
              const float* __restrict__ h_init,   // (H), finite values
              const float* __restrict__ c_init,   // (H)
              float* __restrict__ h_out,          // (S, H), pre-filled 0xFF
              float* __restrict__ c_fin,          // (H) or nullptr
              float* __restrict__ csum_out,       // (H) or nullptr
              int slen)
{
    __shared__ f4 hbuf[256];
    const int tid = threadIdx.x;
    const int g   = blockIdx.x;
    const int wv  = tid >> 6;
    const int lg  = tid & 63;
    const int j   = g * 8 + wv;

    f4 W[4][4];
#pragma unroll
    for (int q = 0; q < 4; ++q)
#pragma unroll
        for (int i = 0; i < 4; ++i)
            W[q][i] = *(const f4*)(Whh + (size_t)(j + q * HDIM) * HDIM
                                   + 4 * lg + 256 * i);

    float c = 0.0f, csum = 0.0f;
    if (lg == 0) c = c_init[j];

    float gnow = G[(size_t)(lg & 3) * HDIM + j];

    for (int t = 0; t < slen; ++t) {
#pragma unroll
        for (int q = 0; q < 4; ++q)
#pragma unroll
            for (int i = 0; i < 4; ++i)
                asm volatile("" : "+v"(W[q][i]));

        const float* hp = (t == 0) ? h_init : (h_out + (size_t)(t - 1) * HDIM);

        if (wv == 0) {
            f4 a, b, cc, d;
            const float* p = hp + 4 * lg;
            for (;;) {
                llc_load_4x4(p, a, b, cc, d);
                if (!__any(any_nan16(a, b, cc, d))) break;
                __builtin_amdgcn_s_sleep(1);
            }
            hbuf[swz(lg)]       = a;
            hbuf[swz(64 + lg)]  = b;
            hbuf[swz(128 + lg)] = cc;
            hbuf[swz(192 + lg)] = d;
        }
        __syncthreads();

        int tn = (t + 1 < slen) ? (t + 1) : t;
        float gnext = G[(size_t)tn * (4 * HDIM) + (lg & 3) * HDIM + j];

        f4 h0 = hbuf[swz(lg)];
        f4 h1 = hbuf[swz(64 + lg)];
        f4 h2 = hbuf[swz(128 + lg)];
        f4 h3 = hbuf[swz(192 + lg)];
        float p0 = 0.f, p1 = 0.f, p2 = 0.f, p3 = 0.f;
        f4 hv;
#pragma unroll
        for (int i = 0; i < 4; ++i) {
            hv = (i == 0) ? h0 : (i == 1) ? h1 : (i == 2) ? h2 : h3;
            p0 = fmaf(W[0][i].x, hv.x, fmaf(W[0][i].y, hv.y,
                 fmaf(W[0][i].z, hv.z, fmaf(W[0][i].w, hv.w, p0))));
            p1 = fmaf(W[1][i].x, hv.x, fmaf(W[1][i].y, hv.y,
                 fmaf(W[1][i].z, hv.z, fmaf(W[1][i].w, hv.w, p1))));
            p2 = fmaf(W[2][i].x, hv.x, fmaf(W[2][i].y, hv.y,
                 fmaf(W[2][i].z, hv.z, fmaf(W[2][i].w, hv.w, p2))));
            p3 = fmaf(W[3][i].x, hv.x, fmaf(W[3][i].y, hv.y,
                 fmaf(W[3][i].z, hv.z, fmaf(W[3][i].w, hv.w, p3))));
        }

        float t01 = __shfl_xor((lg & 1) ? p0 : p1, 1);
        float s01 = ((lg & 1) ? p1 : p0) + t01;
        float t23 = __shfl_xor((lg & 1) ? p2 : p3, 1);
        float s23 = ((lg & 1) ? p3 : p2) + t23;
        float tq  = __shfl_xor((lg & 2) ? s01 : s23, 2);
        float s   = ((lg & 2) ? s23 : s01) + tq;
        s += __shfl_xor(s, 4);
        s += __shfl_xor(s, 8);
        s += __shfl_xor(s, 16);
        s += __shfl_xor(s, 32);

        float pre = s + gnow;
        float act = ((lg & 3) == 2) ? tanhf(pre) : sigmoidf_(pre);
        float a1 = __shfl(act, 1);
        float a2 = __shfl(act, 2);
        float a3 = __shfl(act, 3);

        if (lg == 0) {
            c = a1 * c + act * a2;
            float h = a3 * tanhf(c);
            csum += h;
            agent_storef(h_out + (size_t)t * HDIM + j, h);
        }
        gnow = gnext;
        __syncthreads();
    }

    if (lg == 0) {
        if (c_fin)    c_fin[j]    = c;
        if (csum_out) csum_out[j] = csum;
    }
}

// ctx_bias[r] = dec_b[r] + dot(dec_Wih[r, H:2H], context)
__global__ __launch_bounds__(256)
void ctx_bias_k(const float* __restrict__ dec_Wih,
                const float* __restrict__ dec_b,
                const float* __restrict__ ctx,
                float* __restrict__ out)
{
    const int wv = threadIdx.x >> 6;
    const int lane = threadIdx.x & 63;
    const int r = blockIdx.x * 4 + wv;
    const float* wr = dec_Wih + (size_t)r * (2 * HDIM) + HDIM;
    float s = 0.f;
    for (int k = lane; k < HDIM; k += 64) s += wr[k] * ctx[k];
#pragma unroll
    for (int off = 32; off > 0; off >>= 1) s += __shfl_xor(s, off);
    if (lane == 0) out[r] = s + dec_b[r];
}

// ---------------------------------------------------------------------------
// logits_mfma (round-10/11 proven): C(1024,32000) = dec_h @ out_w^T + out_b,
// bf16x3 split (ah*bh + ah*bl + al*bh, fp32 MFMA accum), fused per-row
// argmax via packed u64 keys + atomicMax.
// Grid (250, 4), 512 threads (8 waves). Tile 256m x 128n, K-chunk 32.
// ---------------------------------------------------------------------------
#define LSTR 40

__global__ __launch_bounds__(512, 1)
void logits_mfma(const float* __restrict__ Amat,   // dec_h (S,H)
                 const float* __restrict__ Bmat,   // out_w (V,H)
                 const float* __restrict__ bias,   // out_b (V)
                 float* __restrict__ C,            // (S,V)
                 unsigned long long* __restrict__ amax)
{
    __shared__ unsigned short Ah[256][LSTR], Al[256][LSTR];
    __shared__ unsigned short Bh[128][LSTR], Bl[128][LSTR];

    const int tid = threadIdx.x;
    const int l   = tid & 63;
    const int w   = tid >> 6;
    const int n0  = blockIdx.x * 128;
    const int m0  = blockIdx.y * 256;
    const int mb  = (w >> 1) * 64;
    const int nb  = (w & 1) * 64;

    f32x4 acc[4][4];
#pragma unroll
    for (int i = 0; i < 4; ++i)
#pragma unroll
        for (int jj = 0; jj < 4; ++jj) acc[i][jj] = (f32x4){0.f, 0.f, 0.f, 0.f};

    for (int k0 = 0; k0 < HDIM; k0 += 32) {
#pragma unroll
        for (int q = 0; q < 4; ++q) {
            int id  = q * 512 + tid;
            int row = id >> 3;
            int kq  = (id & 7) * 4;
            float4 av = *(const float4*)(Amat + (size_t)(m0 + row) * HDIM
                                         + k0 + kq);
            unsigned short h0,h1,h2,h3, l0,l1,l2,l3;
            split_bf16(av.x, h0, l0); split_bf16(av.y, h1, l1);
            split_bf16(av.z, h2, l2); split_bf16(av.w, h3, l3);
            sh4 hi = {(short)h0, (short)h1, (short)h2, (short)h3};
            sh4 lo = {(short)l0, (short)l1, (short)l2, (short)l3};
            *(sh4*)&Ah[row][kq] = hi;
            *(sh4*)&Al[row][kq] = lo;
        }
#pragma unroll
        for (int q = 0; q < 2; ++q) {
            int id  = q * 512 + tid;
            int row = id >> 3;
            int kq  = (id & 7) * 4;
            float4 bv = *(const float4*)(Bmat + (size_t)(n0 + row) * HDIM
                                         + k0 + kq);
            unsigned short h0,h1,h2,h3, l0,l1,l2,l3;
            split_bf16(bv.x, h0, l0); split_bf16(bv.y, h1, l1);
            split_bf16(bv.z, h2, l2); split_bf16(bv.w, h3, l3);
            sh4 hi = {(short)h0, (short)h1, (short)h2, (short)h3};
            sh4 lo = {(short)l0, (short)l1, (short)l2, (short)l3};
            *(sh4*)&Bh[row][kq] = hi;
            *(sh4*)&Bl[row][kq] = lo;
        }
        __syncthreads();

        const int kb = (l >> 4) * 8;
        short8 a_hi[4], a_lo[4], b_hi[4], b_lo[4];
#pragma unroll
        for (int i = 0; i < 4; ++i) {
            int ra = mb + i * 16 + (l & 15);
            int rb = nb + i * 16 + (l & 15);
            a_hi[i] = *(const short8*)&Ah[ra][kb];
            a_lo[i] = *(const short8*)&Al[ra][kb];
            b_hi[i] = *(const short8*)&Bh[rb][kb];
            b_lo[i] = *(const short8*)&Bl[rb][kb];
        }
#pragma unroll
        for (int i = 0; i < 4; ++i)
#pragma unroll
            for (int jj = 0; jj < 4; ++jj) {
                acc[i][jj] = __builtin_amdgcn_mfma_f32_16x16x32_bf16(
                    a_hi[i], b_hi[jj], acc[i][jj], 0, 0, 0);
                acc[i][jj] = __builtin_amdgcn_mfma_f32_16x16x32_bf16(
                    a_hi[i], b_lo[jj], acc[i][jj], 0, 0, 0);
                acc[i][jj] = __builtin_amdgcn_mfma_f32_16x16x32_bf16(
                    a_lo[i], b_hi[jj], acc[i][jj], 0, 0, 0);
            }
        __syncthreads();
    }

    // epilogue: bias, store, fused argmax (packed monotone-float | ~col key)
#pragma unroll
    for (int i = 0; i < 4; ++i) {
        const int mrow = m0 + mb + i * 16 + ((l >> 4) << 2);
        unsigned long long key[4] = {0ull, 0ull, 0ull, 0ull};
#pragma unroll
        for (int jj = 0; jj < 4; ++jj) {
            int n = n0 + nb + jj * 16 + (l & 15);
            float bv = bias[n];
            f32x4 o = acc[i][jj];
#pragma unroll
            for (int r = 0; r < 4; ++r) {
                float val = o[r] + bv;
                C[(size_t)(mrow + r) * VDIM + n] = val;
                unsigned um = __float_as_uint(val);
                um = (um & 0x80000000u) ? ~um : (um | 0x80000000u);
                unsigned long long k2 = ((unsigned long long)um << 32)
                    | (unsigned long long)(0xFFFFFFFFu - (unsigned)n);
                if (k2 > key[r]) key[r] = k2;
            }
        }
#pragma unroll
        for (int r = 0; r < 4; ++r) {
#pragma unroll
            for (int off = 1; off < 16; off <<= 1) {
                unsigned long long other = __shfl_xor(key[r], off);
                if (other > key[r]) key[r] = other;
            }
            if ((l & 15) == 0)
                atomicMax(&amax[mrow + r], key[r]);
        }
    }
}

// decode argmax keys -> float indices
__global__ __launch_bounds__(256)
void idx_final(const unsigned long long* __restrict__ amax,
               float* __restrict__ out_idx)
{
    int i = blockIdx.x * 256 + threadIdx.x;
    if (i < S_LEN) {
        unsigned col = 0xFFFFFFFFu - (unsigned)(amax[i] & 0xFFFFFFFFull);
        out_idx[i] = (float)col;
    }
}

extern "C" void kernel_launch(void* const* d_in, const int* in_sizes, int n_in,
                              void* d_out, int out_size, void* d_ws, size_t ws_size,
                              hipStream_t stream)
{
    (void)in_sizes; (void)n_in; (void)out_size; (void)ws_size;

    const int*   input_seq = (const int*)d_in[0];
    const int*   gold_seq  = (const int*)d_in[1];
    const float* embed     = (const float*)d_in[2];
    const float* enc_Wih   = (const float*)d_in[3];
    const float* enc_Whh   = (const float*)d_in[4];
    const float* enc_b     = (const float*)d_in[5];
    const float* dec_Wih   = (const float*)d_in[6];
    const float* dec_Whh   = (const float*)d_in[7];
    const float* dec_b     = (const float*)d_in[8];
    // d_in[9..14]: attention params — dead code
    const float* out_w     = (const float*)d_in[15];
    const float* out_b     = (const float*)d_in[16];

    float* out = (float*)d_out;
    float* G_enc = out;                 // dead before logits overwrite (serial)
    float* G_dec = out + 4194304;       // dead before logits overwrite (serial)

    // workspace
    char* wsb = (char*)d_ws;
    unsigned long long* amax = (unsigned long long*)wsb;   // 8 KB
    float* zerovec = (float*)(wsb + 8192);                 // 1024 f
    float* c0      = zerovec + 1024;
    float* ctx     = c0 + 1024;
    float* ctxb    = ctx + 1024;                           // 4096 f
    float* enc_out = ctxb + 4096;                          // S*H
    float* dec_h   = enc_out + 1048576;                    // S*H

    hipMemsetAsync(d_ws, 0, 12288, stream);                // amax + zerovec
    hipMemsetAsync(enc_out, 0xFF, (size_t)S_LEN * HDIM * 4, stream);
    hipMemsetAsync(dec_h,   0xFF, (size_t)S_LEN * HDIM * 4, stream);

    // G_enc = embed[input_seq] @ enc_Wih^T + enc_b
    gemm_nt<1><<<dim3(32, 8), 256, 0, stream>>>(
        enc_Wih, HDIM, enc_b, G_enc, 4 * HDIM,
        embed, input_seq, S_LEN, 4 * HDIM, HDIM);

    // encoder
    lstm_seq<<<128, 512, 0, stream>>>(
        enc_Whh, G_enc, zerovec, zerovec, enc_out, c0, ctx, S_LEN);

    // ctxb = dec_b + dec_Wih[:,H:] @ ctx
    ctx_bias_k<<<1024, 256, 0, stream>>>(dec_Wih, dec_b, ctx, ctxb);

    // G_dec = relu(prev) @ dec_Wih[:,:H]^T + ctxb   (context folded as bias)
    gemm_nt<2><<<dim3(32, 8), 256, 0, stream>>>(
        dec_Wih, 2 * HDIM, ctxb, G_dec, 4 * HDIM,
        embed, gold_seq, S_LEN, 4 * HDIM, HDIM);

    // decoder — identical proven kernel, bare G loads
    lstm_seq<<<128, 512, 0, stream>>>(
        dec_Whh, G_dec, enc_out + (size_t)(S_LEN - 1) * HDIM, c0,
        dec_h, nullptr, nullptr, S_LEN);

    // logits (bf16x3 MFMA) + fused argmax
    logits_mfma<<<dim3(VDIM / 128, S_LEN / 256), 512, 0, stream>>>(
        dec_h, out_w, out_b, out, amax);

    // idxs -> d_out[S*V : S*V + S)
    idx_final<<<4, 256, 0, stream>>>(amax, out + (size_t)S_LEN * VDIM);
}

// Round 13
// 4372.499 us; speedup vs baseline: 1.5236x; 1.0784x over previous
//
#include <hip/hip_runtime.h>
#include <math.h>

// Model: S=1024, V=32000, H=1024. Attention dead code => context = sum enc_h.
//
// Round-13 = round-12 (best, 4715us) + two deltas:
//  (a) input GEMMs converted from fp32 vector (~170us each) to the proven
//      bf16x3 MFMA structure (g_mfma, ~60-90us each). G error ~4e-6,
//      contractive through the recurrence.
//  (b) lstm_seq: double-buffered hbuf -> ONE barrier per step. The removed
//      end-barrier only protected hbuf reuse; with hbuf[t&1] a wave can be
//      at most 1 iteration ahead (gated by the post-stage barrier), so the
//      same buffer is rewritten only at t+2, after all waves passed
//      barrier(t+1), i.e. after all iteration-t reads completed.
//
// Pipeline:
//   memsets: amax+zerovec zero; enc_out/dec_h NaN sentinel
//   g_mfma<1>: G_enc = embed[input_seq] @ enc_Wih^T + enc_b
//   lstm_seq : encoder -> enc_out, c0, ctx
//   ctx_bias_k: ctxb = dec_b + dec_Wih[:,H:] @ ctx
//   g_mfma<2>: G_dec = relu(prev) @ dec_Wih[:,:H]^T + ctxb  (bias=ctxb;
//              decoder G loads stay BARE — rounds 9-11: fusing "+gctx" onto
//              the G load forces the vmcnt wait into the current step, +900us)
//   lstm_seq : decoder
//   logits_mfma: bf16x3 MFMA GEMM + bias + fused packed-key argmax
//   idx_final : decode argmax keys -> d_out[S*V..]

#define S_LEN 1024
#define HDIM  1024
#define VDIM  32000

typedef float f4 __attribute__((ext_vector_type(4)));
typedef float f32x4 __attribute__((ext_vector_type(4)));
typedef short short8 __attribute__((ext_vector_type(8)));
typedef short sh4 __attribute__((ext_vector_type(4)));

__device__ __forceinline__ void agent_storef(float* p, float v) {
    __hip_atomic_store(p, v, __ATOMIC_RELAXED, __HIP_MEMORY_SCOPE_AGENT);
}
__device__ __forceinline__ float sigmoidf_(float x) {
    return 1.0f / (1.0f + expf(-x));
}
__device__ __forceinline__ void llc_load_4x4(const float* p, f4& a, f4& b,
                                             f4& c, f4& d) {
    asm volatile(
        "global_load_dwordx4 %0, %4, off sc0 sc1\n\t"
        "global_load_dwordx4 %1, %4, off offset:1024 sc0 sc1\n\t"
        "global_load_dwordx4 %2, %4, off offset:2048 sc0 sc1\n\t"
        "global_load_dwordx4 %3, %4, off offset:3072 sc0 sc1\n\t"
        "s_waitcnt vmcnt(0)"
        : "=&v"(a), "=&v"(b), "=&v"(c), "=&v"(d)
        : "v"(p) : "memory");
}
__device__ __forceinline__ bool any_nan16(f4 a, f4 b, f4 c, f4 d) {
    float s0 = (a.x + a.y) + (a.z + a.w);
    float s1 = (b.x + b.y) + (b.z + b.w);
    float s2 = (c.x + c.y) + (c.z + c.w);
    float s3 = (d.x + d.y) + (d.z + d.w);
    float s  = (s0 + s1) + (s2 + s3);
    return s != s;
}
__device__ __forceinline__ int swz(int s) {
    return (s & ~7) | ((s ^ (s >> 3)) & 7);
}
// RNE split: x = hi + lo with |lo| <= 2^-9 |x|, both bf16.
__device__ __forceinline__ void split_bf16(float x, unsigned short& h,
                                           unsigned short& l) {
    unsigned u = __float_as_uint(x);
    unsigned hr = (u + 0x7FFFu + ((u >> 16) & 1u)) >> 16;
    h = (unsigned short)hr;
    float hf = __uint_as_float(hr << 16);
    float r = x - hf;
    unsigned v = __float_as_uint(r);
    l = (unsigned short)((v + 0x7FFFu + ((v >> 16) & 1u)) >> 16);
}

#define LSTR 40

// ---------------------------------------------------------------------------
// g_mfma: input GEMMs in bf16x3 MFMA (logits_mfma structure, no argmax).
// C(M,N) = A_eff(M,1024) @ B(N,1024)^T + bias[n]
// MODE 1: A_eff[m] = embed[gidx[m]]
// MODE 2: A_eff[0] = 0; A_eff[m] = relu(embed[gidx[m-1]])
// Grid (N/128, M/256), 512 threads (8 waves). Tile 256m x 128n, K-chunk 32.
// ---------------------------------------------------------------------------
template<int MODE>
__global__ __launch_bounds__(512, 1)
void g_mfma(const float* __restrict__ B, int ldb,
            const float* __restrict__ bias,
            float* __restrict__ C, int ldc,
            const float* __restrict__ embed,
            const int* __restrict__ gidx)
{
    __shared__ unsigned short Ah[256][LSTR], Al[256][LSTR];
    __shared__ unsigned short Bh[128][LSTR], Bl[128][LSTR];

    const int tid = threadIdx.x;
    const int l   = tid & 63;
    const int w   = tid >> 6;
    const int n0  = blockIdx.x * 128;
    const int m0  = blockIdx.y * 256;
    const int mb  = (w >> 1) * 64;
    const int nb  = (w & 1) * 64;

    // preload gather rows for the 4 A-rows this thread stages each chunk
    int  arow[4];
    bool azero[4];
#pragma unroll
    for (int q = 0; q < 4; ++q) {
        int row = (q * 512 + tid) >> 3;
        int m = m0 + row;
        if (MODE == 1) { arow[q] = gidx[m]; azero[q] = false; }
        else { azero[q] = (m == 0); arow[q] = azero[q] ? 0 : gidx[m - 1]; }
    }

    f32x4 acc[4][4];
#pragma unroll
    for (int i = 0; i < 4; ++i)
#pragma unroll
        for (int jj = 0; jj < 4; ++jj) acc[i][jj] = (f32x4){0.f, 0.f, 0.f, 0.f};

    for (int k0 = 0; k0 < HDIM; k0 += 32) {
#pragma unroll
        for (int q = 0; q < 4; ++q) {
            int id  = q * 512 + tid;
            int row = id >> 3;
            int kq  = (id & 7) * 4;
            float4 av;
            if (MODE == 2 && azero[q]) {
                av = make_float4(0.f, 0.f, 0.f, 0.f);
            } else {
                av = *(const float4*)(embed + (size_t)arow[q] * HDIM + k0 + kq);
                if (MODE == 2) {
                    av.x = fmaxf(av.x, 0.f); av.y = fmaxf(av.y, 0.f);
                    av.z = fmaxf(av.z, 0.f); av.w = fmaxf(av.w, 0.f);
                }
            }
            unsigned short h0,h1,h2,h3, l0,l1,l2,l3;
            split_bf16(av.x, h0, l0); split_bf16(av.y, h1, l1);
            split_bf16(av.z, h2, l2); split_bf16(av.w, h3, l3);
            sh4 hi = {(short)h0, (short)h1, (short)h2, (short)h3};
            sh4 lo = {(short)l0, (short)l1, (short)l2, (short)l3};
            *(sh4*)&Ah[row][kq] = hi;
            *(sh4*)&Al[row][kq] = lo;
        }
#pragma unroll
        for (int q = 0; q < 2; ++q) {
            int id  = q * 512 + tid;
            int row = id >> 3;
            int kq  = (id & 7) * 4;
            float4 bv = *(const float4*)(B + (size_t)(n0 + row) * ldb
                                         + k0 + kq);
            unsigned short h0,h1,h2,h3, l0,l1,l2,l3;
            split_bf16(bv.x, h0, l0); split_bf16(bv.y, h1, l1);
            split_bf16(bv.z, h2, l2); split_bf16(bv.w, h3, l3);
            sh4 hi = {(short)h0, (short)h1, (short)h2, (short)h3};
            sh4 lo = {(short)l0, (short)l1, (short)l2, (short)l3};
            *(sh4*)&Bh[row][kq] = hi;
            *(sh4*)&Bl[row][kq] = lo;
        }
        __syncthreads();

        const int kb = (l >> 4) * 8;
        short8 a_hi[4], a_lo[4], b_hi[4], b_lo[4];
#pragma unroll
        for (int i = 0; i < 4; ++i) {
            int ra = mb + i * 16 + (l & 15);
            int rb = nb + i * 16 + (l & 15);
            a_hi[i] = *(const short8*)&Ah[ra][kb];
            a_lo[i] = *(const short8*)&Al[ra][kb];
            b_hi[i] = *(const short8*)&Bh[rb][kb];
            b_lo[i] = *(const short8*)&Bl[rb][kb];
        }
#pragma unroll
        for (int i = 0; i < 4; ++i)
#pragma unroll
            for (int jj = 0; jj < 4; ++jj) {
                acc[i][jj] = __builtin_amdgcn_mfma_f32_16x16x32_bf16(
                    a_hi[i], b_hi[jj], acc[i][jj], 0, 0, 0);
                acc[i][jj] = __builtin_amdgcn_mfma_f32_16x16x32_bf16(
                    a_hi[i], b_lo[jj], acc[i][jj], 0, 0, 0);
                acc[i][jj] = __builtin_amdgcn_mfma_f32_16x16x32_bf16(
                    a_lo[i], b_hi[jj], acc[i][jj], 0, 0, 0);
            }
        __syncthreads();
    }

    // epilogue: bias + store
#pragma unroll
    for (int i = 0; i < 4; ++i) {
        const int mrow = m0 + mb + i * 16 + ((l >> 4) << 2);
#pragma unroll
        for (int jj = 0; jj < 4; ++jj) {
            int n = n0 + nb + jj * 16 + (l & 15);
            float bv = bias[n];
            f32x4 o = acc[i][jj];
#pragma unroll
            for (int r = 0; r < 4; ++r)
                C[(size_t)(mrow + r) * ldc + n] = o[r] + bv;
        }
    }
}

// ---------------------------------------------------------------------------
// Persistent sequential LSTM — round-5 proven body, double-buffered hbuf,
// ONE barrier per step. 128 WGs x 512 threads; sentinel-poll sync; bare G
// loads (waitcnt sinks to next iteration). Used for encoder AND decoder.
// ---------------------------------------------------------------------------
__global__ __launch_bounds__(512, 2)
void lstm_seq(const float* __restrict__ Whh,
              const float* __restrict__ G,        // (S, 4H) preactivations
              const float* __restrict__ h_init,   // (H), finite values
              const float* __restrict__ c_init,   // (H)
              float* __restrict__ h_out,          // (S, H), pre-filled 0xFF
              float* __restrict__ c_fin,          // (H) or nullptr
              float* __restrict__ csum_out,       // (H) or nullptr
              int slen)
{
    __shared__ f4 hbuf[2][256];
    const int tid = threadIdx.x;
    const int g   = blockIdx.x;
    const int wv  = tid >> 6;
    const int lg  = tid & 63;
    const int j   = g * 8 + wv;

    f4 W[4][4];
#pragma unroll
    for (int q = 0; q < 4; ++q)
#pragma unroll
        for (int i = 0; i < 4; ++i)
            W[q][i] = *(const f4*)(Whh + (size_t)(j + q * HDIM) * HDIM
                                   + 4 * lg + 256 * i);

    float c = 0.0f, csum = 0.0f;
    if (lg == 0) c = c_init[j];

    float gnow = G[(size_t)(lg & 3) * HDIM + j];

    for (int t = 0; t < slen; ++t) {
#pragma unroll
        for (int q = 0; q < 4; ++q)
#pragma unroll
            for (int i = 0; i < 4; ++i)
                asm volatile("" : "+v"(W[q][i]));

        const float* hp = (t == 0) ? h_init : (h_out + (size_t)(t - 1) * HDIM);
        f4* hb = hbuf[t & 1];

        if (wv == 0) {
            f4 a, b, cc, d;
            const float* p = hp + 4 * lg;
            for (;;) {
                llc_load_4x4(p, a, b, cc, d);
                if (!__any(any_nan16(a, b, cc, d))) break;
                __builtin_amdgcn_s_sleep(1);
            }
            hb[swz(lg)]       = a;
            hb[swz(64 + lg)]  = b;
            hb[swz(128 + lg)] = cc;
            hb[swz(192 + lg)] = d;
        }
        __syncthreads();

        int tn = (t + 1 < slen) ? (t + 1) : t;
        float gnext = G[(size_t)tn * (4 * HDIM) + (lg & 3) * HDIM + j];

        f4 h0 = hb[swz(lg)];
        f4 h1 = hb[swz(64 + lg)];
        f4 h2 = hb[swz(128 + lg)];
        f4 h3 = hb[swz(192 + lg)];
        float p0 = 0.f, p1 = 0.f, p2 = 0.f, p3 = 0.f;
        f4 hv;
#pragma unroll
        for (int i = 0; i < 4; ++i) {
            hv = (i == 0) ? h0 : (i == 1) ? h1 : (i == 2) ? h2 : h3;
            p0 = fmaf(W[0][i].x, hv.x, fmaf(W[0][i].y, hv.y,
                 fmaf(W[0][i].z, hv.z, fmaf(W[0][i].w, hv.w, p0))));
            p1 = fmaf(W[1][i].x, hv.x, fmaf(W[1][i].y, hv.y,
                 fmaf(W[1][i].z, hv.z, fmaf(W[1][i].w, hv.w, p1))));
            p2 = fmaf(W[2][i].x, hv.x, fmaf(W[2][i].y, hv.y,
                 fmaf(W[2][i].z, hv.z, fmaf(W[2][i].w, hv.w, p2))));
            p3 = fmaf(W[3][i].x, hv.x, fmaf(W[3][i].y, hv.y,
                 fmaf(W[3][i].z, hv.z, fmaf(W[3][i].w, hv.w, p3))));
        }

        float t01 = __shfl_xor((lg & 1) ? p0 : p1, 1);
        float s01 = ((lg & 1) ? p1 : p0) + t01;
        float t23 = __shfl_xor((lg & 1) ? p2 : p3, 1);
        float s23 = ((lg & 1) ? p3 : p2) + t23;
        float tq  = __shfl_xor((lg & 2) ? s01 : s23, 2);
        float s   = ((lg & 2) ? s23 : s01) + tq;
        s += __shfl_xor(s, 4);
        s += __shfl_xor(s, 8);
        s += __shfl_xor(s, 16);
        s += __shfl_xor(s, 32);

        float pre = s + gnow;
        float act = ((lg & 3) == 2) ? tanhf(pre) : sigmoidf_(pre);
        float a1 = __shfl(act, 1);
        float a2 = __shfl(act, 2);
        float a3 = __shfl(act, 3);

        if (lg == 0) {
            c = a1 * c + act * a2;
            float h = a3 * tanhf(c);
            csum += h;
            agent_storef(h_out + (size_t)t * HDIM + j, h);
        }
        gnow = gnext;
        // no end barrier: hbuf is double-buffered; the post-stage barrier
        // bounds wave skew to 1 iteration, so hbuf[t&1] is reused only at
        // t+2, after all iteration-t reads completed.
    }

    if (lg == 0) {
        if (c_fin)    c_fin[j]    = c;
        if (csum_out) csum_out[j] = csum;
    }
}

// ctx_bias[r] = dec_b[r] + dot(dec_Wih[r, H:2H], context)
__global__ __launch_bounds__(256)
void ctx_bias_k(const float* __restrict__ dec_Wih,
                const float* __restrict__ dec_b,
                const float* __restrict__ ctx,
                float* __restrict__ out)
{
    const int wv = threadIdx.x >> 6;
    const int lane = threadIdx.x & 63;
    const int r = blockIdx.x * 4 + wv;
    const float* wr = dec_Wih + (size_t)r * (2 * HDIM) + HDIM;
    float s = 0.f;
    for (int k = lane; k < HDIM; k += 64) s += wr[k] * ctx[k];
#pragma unroll
    for (int off = 32; off > 0; off >>= 1) s += __shfl_xor(s, off);
    if (lane == 0) out[r] = s + dec_b[r];
}

// ---------------------------------------------------------------------------
// logits_mfma (proven rounds 10-12): C = dec_h @ out_w^T + out_b, bf16x3,
// fused per-row argmax via packed u64 keys + atomicMax.
// Grid (250, 4), 512 threads. Tile 256m x 128n, K-chunk 32.
// ---------------------------------------------------------------------------
__global__ __launch_bounds__(512, 1)
void logits_mfma(const float* __restrict__ Amat,   // dec_h (S,H)
                 const float* __restrict__ Bmat,   // out_w (V,H)
                 const float* __restrict__ bias,   // out_b (V)
                 float* __restrict__ C,            // (S,V)
                 unsigned long long* __restrict__ amax)
{
    __shared__ unsigned short Ah[256][LSTR], Al[256][LSTR];
    __shared__ unsigned short Bh[128][LSTR], Bl[128][LSTR];

    const int tid = threadIdx.x;
    const int l   = tid & 63;
    const int w   = tid >> 6;
    const int n0  = blockIdx.x * 128;
    const int m0  = blockIdx.y * 256;
    const int mb  = (w >> 1) * 64;
    const int nb  = (w & 1) * 64;

    f32x4 acc[4][4];
#pragma unroll
    for (int i = 0; i < 4; ++i)
#pragma unroll
        for (int jj = 0; jj < 4; ++jj) acc[i][jj] = (f32x4){0.f, 0.f, 0.f, 0.f};

    for (int k0 = 0; k0 < HDIM; k0 += 32) {
#pragma unroll
        for (int q = 0; q < 4; ++q) {
            int id  = q * 512 + tid;
            int row = id >> 3;
            int kq  = (id & 7) * 4;
            float4 av = *(const float4*)(Amat + (size_t)(m0 + row) * HDIM
                                         + k0 + kq);
            unsigned short h0,h1,h2,h3, l0,l1,l2,l3;
            split_bf16(av.x, h0, l0); split_bf16(av.y, h1, l1);
            split_bf16(av.z, h2, l2); split_bf16(av.w, h3, l3);
            sh4 hi = {(short)h0, (short)h1, (short)h2, (short)h3};
            sh4 lo = {(short)l0, (short)l1, (short)l2, (short)l3};
            *(sh4*)&Ah[row][kq] = hi;
            *(sh4*)&Al[row][kq] = lo;
        }
#pragma unroll
        for (int q = 0; q < 2; ++q) {
            int id  = q * 512 + tid;
            int row = id >> 3;
            int kq  = (id & 7) * 4;
            float4 bv = *(const float4*)(Bmat + (size_t)(n0 + row) * HDIM
                                         + k0 + kq);
            unsigned short h0,h1,h2,h3, l0,l1,l2,l3;
            split_bf16(bv.x, h0, l0); split_bf16(bv.y, h1, l1);
            split_bf16(bv.z, h2, l2); split_bf16(bv.w, h3, l3);
            sh4 hi = {(short)h0, (short)h1, (short)h2, (short)h3};
            sh4 lo = {(short)l0, (short)l1, (short)l2, (short)l3};
            *(sh4*)&Bh[row][kq] = hi;
            *(sh4*)&Bl[row][kq] = lo;
        }
        __syncthreads();

        const int kb = (l >> 4) * 8;
        short8 a_hi[4], a_lo[4], b_hi[4], b_lo[4];
#pragma unroll
        for (int i = 0; i < 4; ++i) {
            int ra = mb + i * 16 + (l & 15);
            int rb = nb + i * 16 + (l & 15);
            a_hi[i] = *(const short8*)&Ah[ra][kb];
            a_lo[i] = *(const short8*)&Al[ra][kb];
            b_hi[i] = *(const short8*)&Bh[rb][kb];
            b_lo[i] = *(const short8*)&Bl[rb][kb];
        }
#pragma unroll
        for (int i = 0; i < 4; ++i)
#pragma unroll
            for (int jj = 0; jj < 4; ++jj) {
                acc[i][jj] = __builtin_amdgcn_mfma_f32_16x16x32_bf16(
                    a_hi[i], b_hi[jj], acc[i][jj], 0, 0, 0);
                acc[i][jj] = __builtin_amdgcn_mfma_f32_16x16x32_bf16(
                    a_hi[i], b_lo[jj], acc[i][jj], 0, 0, 0);
                acc[i][jj] = __builtin_amdgcn_mfma_f32_16x16x32_bf16(
                    a_lo[i], b_hi[jj], acc[i][jj], 0, 0, 0);
            }
        __syncthreads();
    }

    // epilogue: bias, store, fused argmax (packed monotone-float | ~col key)
#pragma unroll
    for (int i = 0; i < 4; ++i) {
        const int mrow = m0 + mb + i * 16 + ((l >> 4) << 2);
        unsigned long long key[4] = {0ull, 0ull, 0ull, 0ull};
#pragma unroll
        for (int jj = 0; jj < 4; ++jj) {
            int n = n0 + nb + jj * 16 + (l & 15);
            float bv = bias[n];
            f32x4 o = acc[i][jj];
#pragma unroll
            for (int r = 0; r < 4; ++r) {
                float val = o[r] + bv;
                C[(size_t)(mrow + r) * VDIM + n] = val;
                unsigned um = __float_as_uint(val);
                um = (um & 0x80000000u) ? ~um : (um | 0x80000000u);
                unsigned long long k2 = ((unsigned long long)um << 32)
                    | (unsigned long long)(0xFFFFFFFFu - (unsigned)n);
                if (k2 > key[r]) key[r] = k2;
            }
        }
#pragma unroll
        for (int r = 0; r < 4; ++r) {
#pragma unroll
            for (int off = 1; off < 16; off <<= 1) {
                unsigned long long other = __shfl_xor(key[r], off);
                if (other > key[r]) key[r] = other;
            }
            if ((l & 15) == 0)
                atomicMax(&amax[mrow + r], key[r]);
        }
    }
}

// decode argmax keys -> float indices
__global__ __launch_bounds__(256)
void idx_final(const unsigned long long* __restrict__ amax,
               float* __restrict__ out_idx)
{
    int i = blockIdx.x * 256 + threadIdx.x;
    if (i < S_LEN) {
        unsigned col = 0xFFFFFFFFu - (unsigned)(amax[i] & 0xFFFFFFFFull);
        out_idx[i] = (float)col;
    }
}

extern "C" void kernel_launch(void* const* d_in, const int* in_sizes, int n_in,
                              void* d_out, int out_size, void* d_ws, size_t ws_size,
                              hipStream_t stream)
{
    (void)in_sizes; (void)n_in; (void)out_size; (void)ws_size;

    const int*   input_seq = (const int*)d_in[0];
    const int*   gold_seq  = (const int*)d_in[1];
    const float* embed     = (const float*)d_in[2];
    const float* enc_Wih   = (const float*)d_in[3];
    const float* enc_Whh   = (const float*)d_in[4];
    const float* enc_b     = (const float*)d_in[5];
    const float* dec_Wih   = (const float*)d_in[6];
    const float* dec_Whh   = (const float*)d_in[7];
    const float* dec_b     = (const float*)d_in[8];
    // d_in[9..14]: attention params — dead code
    const float* out_w     = (const float*)d_in[15];
    const float* out_b     = (const float*)d_in[16];

    float* out = (float*)d_out;
    float* G_enc = out;                 // dead before logits overwrite (serial)
    float* G_dec = out + 4194304;       // dead before logits overwrite (serial)

    // workspace
    char* wsb = (char*)d_ws;
    unsigned long long* amax = (unsigned long long*)wsb;   // 8 KB
    float* zerovec = (float*)(wsb + 8192);                 // 1024 f
    float* c0      = zerovec + 1024;
    float* ctx     = c0 + 1024;
    float* ctxb    = ctx + 1024;                           // 4096 f
    float* enc_out = ctxb + 4096;                          // S*H
    float* dec_h   = enc_out + 1048576;                    // S*H

    hipMemsetAsync(d_ws, 0, 12288, stream);                // amax + zerovec
    hipMemsetAsync(enc_out, 0xFF, (size_t)S_LEN * HDIM * 4, stream);
    hipMemsetAsync(dec_h,   0xFF, (size_t)S_LEN * HDIM * 4, stream);

    // G_enc = embed[input_seq] @ enc_Wih^T + enc_b  (bf16x3 MFMA)
    g_mfma<1><<<dim3(32, 4), 512, 0, stream>>>(
        enc_Wih, HDIM, enc_b, G_enc, 4 * HDIM, embed, input_seq);

    // encoder
    lstm_seq<<<128, 512, 0, stream>>>(
        enc_Whh, G_enc, zerovec, zerovec, enc_out, c0, ctx, S_LEN);

    // ctxb = dec_b + dec_Wih[:,H:] @ ctx
    ctx_bias_k<<<1024, 256, 0, stream>>>(dec_Wih, dec_b, ctx, ctxb);

    // G_dec = relu(prev) @ dec_Wih[:,:H]^T + ctxb  (bf16x3 MFMA, bias=ctxb)
    g_mfma<2><<<dim3(32, 4), 512, 0, stream>>>(
        dec_Wih, 2 * HDIM, ctxb, G_dec, 4 * HDIM, embed, gold_seq);

    // decoder — identical proven kernel, bare G loads
    lstm_seq<<<128, 512, 0, stream>>>(
        dec_Whh, G_dec, enc_out + (size_t)(S_LEN - 1) * HDIM, c0,
        dec_h, nullptr, nullptr, S_LEN);

    // logits (bf16x3 MFMA) + fused argmax
    logits_mfma<<<dim3(VDIM / 128, S_LEN / 256), 512, 0, stream>>>(
        dec_h, out_w, out_b, out, amax);

    // idxs -> d_out[S*V : S*V + S)
    idx_final<<<4, 256, 0, stream>>>(amax, out + (size_t)S_LEN * VDIM);
}

// Round 14
// 4323.844 us; speedup vs baseline: 1.5408x; 1.0113x over previous
//
#include <hip/hip_runtime.h>
#include <math.h>

// Model: S=1024, V=32000, H=1024. Attention dead code => context = sum enc_h.
//
// Round-14 = round-13 (best, 4372us) + three safe deltas:
//  (a) g_mfma<1> and g_mfma<2> merged into ONE full-chip launch (grid 32x8)
//      run BEFORE the encoder (each alone used half the chip serially).
//      G_dec is produced WITHOUT ctxb; a tiny gdec_add broadcast kernel
//      applies ctxb after ctx_bias. Decoder G loads stay BARE (round-12
//      mechanism): the vmcnt for a bare G load is deferred one full
//      iteration, so even HBM-cold G is fully hidden.
//  (b) logits_mfma grid transposed to (4,250): the 4 m-tile blocks sharing
//      a B-tile dispatch adjacently -> B served from LLC, not 4x HBM.
//  (c) unchanged otherwise.
//
// Pipeline:
//   memsets | g_mfma_both | lstm_seq(enc) | ctx_bias_k | gdec_add |
//   lstm_seq(dec) | logits_mfma(+argmax) | idx_final

#define S_LEN 1024
#define HDIM  1024
#define VDIM  32000

typedef float f4 __attribute__((ext_vector_type(4)));
typedef float f32x4 __attribute__((ext_vector_type(4)));
typedef short short8 __attribute__((ext_vector_type(8)));
typedef short sh4 __attribute__((ext_vector_type(4)));

__device__ __forceinline__ void agent_storef(float* p, float v) {
    __hip_atomic_store(p, v, __ATOMIC_RELAXED, __HIP_MEMORY_SCOPE_AGENT);
}
__device__ __forceinline__ float sigmoidf_(float x) {
    return 1.0f / (1.0f + expf(-x));
}
__device__ __forceinline__ void llc_load_4x4(const float* p, f4& a, f4& b,
                                             f4& c, f4& d) {
    asm volatile(
        "global_load_dwordx4 %0, %4, off sc0 sc1\n\t"
        "global_load_dwordx4 %1, %4, off offset:1024 sc0 sc1\n\t"
        "global_load_dwordx4 %2, %4, off offset:2048 sc0 sc1\n\t"
        "global_load_dwordx4 %3, %4, off offset:3072 sc0 sc1\n\t"
        "s_waitcnt vmcnt(0)"
        : "=&v"(a), "=&v"(b), "=&v"(c), "=&v"(d)
        : "v"(p) : "memory");
}
__device__ __forceinline__ bool any_nan16(f4 a, f4 b, f4 c, f4 d) {
    float s0 = (a.x + a.y) + (a.z + a.w);
    float s1 = (b.x + b.y) + (b.z + b.w);
    float s2 = (c.x + c.y) + (c.z + c.w);
    float s3 = (d.x + d.y) + (d.z + d.w);
    float s  = (s0 + s1) + (s2 + s3);
    return s != s;
}
__device__ __forceinline__ int swz(int s) {
    return (s & ~7) | ((s ^ (s >> 3)) & 7);
}
// RNE split: x = hi + lo with |lo| <= 2^-9 |x|, both bf16.
__device__ __forceinline__ void split_bf16(float x, unsigned short& h,
                                           unsigned short& l) {
    unsigned u = __float_as_uint(x);
    unsigned hr = (u + 0x7FFFu + ((u >> 16) & 1u)) >> 16;
    h = (unsigned short)hr;
    float hf = __uint_as_float(hr << 16);
    float r = x - hf;
    unsigned v = __float_as_uint(r);
    l = (unsigned short)((v + 0x7FFFu + ((v >> 16) & 1u)) >> 16);
}

#define LSTR 40

// ---------------------------------------------------------------------------
// bf16x3 MFMA GEMM tile body (proven structure). 512 threads, 256m x 128n,
// K-chunk 32. MODE 1: A=embed[gidx[m]], bias!=null. MODE 2:
// A=relu(embed[gidx[m-1]]), row0=0, bias may be null (added later).
// ---------------------------------------------------------------------------
template<int MODE>
__device__ void g_body(const float* __restrict__ B, int ldb,
                       const float* __restrict__ bias,
                       float* __restrict__ C, int ldc,
                       const float* __restrict__ embed,
                       const int* __restrict__ gidx,
                       int bx, int byy)
{
    __shared__ unsigned short Ah[256][LSTR], Al[256][LSTR];
    __shared__ unsigned short Bh[128][LSTR], Bl[128][LSTR];

    const int tid = threadIdx.x;
    const int l   = tid & 63;
    const int w   = tid >> 6;
    const int n0  = bx * 128;
    const int m0  = byy * 256;
    const int mb  = (w >> 1) * 64;
    const int nb  = (w & 1) * 64;

    int  arow[4];
    bool azero[4];
#pragma unroll
    for (int q = 0; q < 4; ++q) {
        int row = (q * 512 + tid) >> 3;
        int m = m0 + row;
        if (MODE == 1) { arow[q] = gidx[m]; azero[q] = false; }
        else { azero[q] = (m == 0); arow[q] = azero[q] ? 0 : gidx[m - 1]; }
    }

    f32x4 acc[4][4];
#pragma unroll
    for (int i = 0; i < 4; ++i)
#pragma unroll
        for (int jj = 0; jj < 4; ++jj) acc[i][jj] = (f32x4){0.f, 0.f, 0.f, 0.f};

    for (int k0 = 0; k0 < HDIM; k0 += 32) {
#pragma unroll
        for (int q = 0; q < 4; ++q) {
            int id  = q * 512 + tid;
            int row = id >> 3;
            int kq  = (id & 7) * 4;
            float4 av;
            if (MODE == 2 && azero[q]) {
                av = make_float4(0.f, 0.f, 0.f, 0.f);
            } else {
                av = *(const float4*)(embed + (size_t)arow[q] * HDIM + k0 + kq);
                if (MODE == 2) {
                    av.x = fmaxf(av.x, 0.f); av.y = fmaxf(av.y, 0.f);
                    av.z = fmaxf(av.z, 0.f); av.w = fmaxf(av.w, 0.f);
                }
            }
            unsigned short h0,h1,h2,h3, l0,l1,l2,l3;
            split_bf16(av.x, h0, l0); split_bf16(av.y, h1, l1);
            split_bf16(av.z, h2, l2); split_bf16(av.w, h3, l3);
            sh4 hi = {(short)h0, (short)h1, (short)h2, (short)h3};
            sh4 lo = {(short)l0, (short)l1, (short)l2, (short)l3};
            *(sh4*)&Ah[row][kq] = hi;
            *(sh4*)&Al[row][kq] = lo;
        }
#pragma unroll
        for (int q = 0; q < 2; ++q) {
            int id  = q * 512 + tid;
            int row = id >> 3;
            int kq  = (id & 7) * 4;
            float4 bv = *(const float4*)(B + (size_t)(n0 + row) * ldb
                                         + k0 + kq);
            unsigned short h0,h1,h2,h3, l0,l1,l2,l3;
            split_bf16(bv.x, h0, l0); split_bf16(bv.y, h1, l1);
            split_bf16(bv.z, h2, l2); split_bf16(bv.w, h3, l3);
            sh4 hi = {(short)h0, (short)h1, (short)h2, (short)h3};
            sh4 lo = {(short)l0, (short)l1, (short)l2, (short)l3};
            *(sh4*)&Bh[row][kq] = hi;
            *(sh4*)&Bl[row][kq] = lo;
        }
        __syncthreads();

        const int kb = (l >> 4) * 8;
        short8 a_hi[4], a_lo[4], b_hi[4], b_lo[4];
#pragma unroll
        for (int i = 0; i < 4; ++i) {
            int ra = mb + i * 16 + (l & 15);
            int rb = nb + i * 16 + (l & 15);
            a_hi[i] = *(const short8*)&Ah[ra][kb];
            a_lo[i] = *(const short8*)&Al[ra][kb];
            b_hi[i] = *(const short8*)&Bh[rb][kb];
            b_lo[i] = *(const short8*)&Bl[rb][kb];
        }
#pragma unroll
        for (int i = 0; i < 4; ++i)
#pragma unroll
            for (int jj = 0; jj < 4; ++jj) {
                acc[i][jj] = __builtin_amdgcn_mfma_f32_16x16x32_bf16(
                    a_hi[i], b_hi[jj], acc[i][jj], 0, 0, 0);
                acc[i][jj] = __builtin_amdgcn_mfma_f32_16x16x32_bf16(
                    a_hi[i], b_lo[jj], acc[i][jj], 0, 0, 0);
                acc[i][jj] = __builtin_amdgcn_mfma_f32_16x16x32_bf16(
                    a_lo[i], b_hi[jj], acc[i][jj], 0, 0, 0);
            }
        __syncthreads();
    }

#pragma unroll
    for (int i = 0; i < 4; ++i) {
        const int mrow = m0 + mb + i * 16 + ((l >> 4) << 2);
#pragma unroll
        for (int jj = 0; jj < 4; ++jj) {
            int n = n0 + nb + jj * 16 + (l & 15);
            float bv = bias ? bias[n] : 0.f;
            f32x4 o = acc[i][jj];
#pragma unroll
            for (int r = 0; r < 4; ++r)
                C[(size_t)(mrow + r) * ldc + n] = o[r] + bv;
        }
    }
}

// both input GEMMs, one full-chip launch: by<4 -> G_enc, else G_dec (no bias)
__global__ __launch_bounds__(512, 1)
void g_mfma_both(const float* __restrict__ embed,
                 const int* __restrict__ input_seq,
                 const int* __restrict__ gold_seq,
                 const float* __restrict__ enc_Wih,
                 const float* __restrict__ enc_b,
                 const float* __restrict__ dec_Wih,
                 float* __restrict__ G_enc,
                 float* __restrict__ G_dec)
{
    const int by = blockIdx.y;
    if (by < 4)
        g_body<1>(enc_Wih, HDIM, enc_b, G_enc, 4 * HDIM,
                  embed, input_seq, blockIdx.x, by);
    else
        g_body<2>(dec_Wih, 2 * HDIM, nullptr, G_dec, 4 * HDIM,
                  embed, gold_seq, blockIdx.x, by - 4);
}

// G_dec[t][:] += ctxb[:]  (broadcast add, 1024 blocks x 256 thr)
__global__ __launch_bounds__(256)
void gdec_add(float* __restrict__ G, const float* __restrict__ ctxb)
{
    const int row = blockIdx.x;
    float* gp = G + (size_t)row * (4 * HDIM);
#pragma unroll
    for (int q = 0; q < 4; ++q) {
        int idx = (q * 256 + threadIdx.x) * 4;
        f4 v = *(f4*)(gp + idx);
        f4 b = *(const f4*)(ctxb + idx);
        v.x += b.x; v.y += b.y; v.z += b.z; v.w += b.w;
        *(f4*)(gp + idx) = v;
    }
}

// ---------------------------------------------------------------------------
// Persistent sequential LSTM — round-13 proven (double-buffered hbuf, one
// barrier/step, sentinel poll, bare G loads). Encoder AND decoder.
// ---------------------------------------------------------------------------
__global__ __launch_bounds__(512, 2)
void lstm_seq(const float* __restrict__ Whh,
              const float* __restrict__ G,        // (S, 4H) preactivations
              const float* __restrict__ h_init,   // (H), finite values
              const float* __restrict__ c_init,   // (H)
              float* __restrict__ h_out,          // (S, H), pre-filled 0xFF
              float* __restrict__ c_fin,          // (H) or nullptr
              float* __restrict__ csum_out,       // (H) or nullptr
              int slen)
{
    __shared__ f4 hbuf[2][256];
    const int tid = threadIdx.x;
    const int g   = blockIdx.x;
    const int wv  = tid >> 6;
    const int lg  = tid & 63;
    const int j   = g * 8 + wv;

    f4 W[4][4];
#pragma unroll
    for (int q = 0; q < 4; ++q)
#pragma unroll
        for (int i = 0; i < 4; ++i)
            W[q][i] = *(const f4*)(Whh + (size_t)(j + q * HDIM) * HDIM
                                   + 4 * lg + 256 * i);

    float c = 0.0f, csum = 0.0f;
    if (lg == 0) c = c_init[j];

    float gnow = G[(size_t)(lg & 3) * HDIM + j];

    for (int t = 0; t < slen; ++t) {
#pragma unroll
        for (int q = 0; q < 4; ++q)
#pragma unroll
            for (int i = 0; i < 4; ++i)
                asm volatile("" : "+v"(W[q][i]));

        const float* hp = (t == 0) ? h_init : (h_out + (size_t)(t - 1) * HDIM);
        f4* hb = hbuf[t & 1];

        if (wv == 0) {
            f4 a, b, cc, d;
            const float* p = hp + 4 * lg;
            for (;;) {
                llc_load_4x4(p, a, b, cc, d);
                if (!__any(any_nan16(a, b, cc, d))) break;
                __builtin_amdgcn_s_sleep(1);
            }
            hb[swz(lg)]       = a;
            hb[swz(64 + lg)]  = b;
            hb[swz(128 + lg)] = cc;
            hb[swz(192 + lg)] = d;
        }
        __syncthreads();

        int tn = (t + 1 < slen) ? (t + 1) : t;
        float gnext = G[(size_t)tn * (4 * HDIM) + (lg & 3) * HDIM + j];

        f4 h0 = hb[swz(lg)];
        f4 h1 = hb[swz(64 + lg)];
        f4 h2 = hb[swz(128 + lg)];
        f4 h3 = hb[swz(192 + lg)];
        float p0 = 0.f, p1 = 0.f, p2 = 0.f, p3 = 0.f;
        f4 hv;
#pragma unroll
        for (int i = 0; i < 4; ++i) {
            hv = (i == 0) ? h0 : (i == 1) ? h1 : (i == 2) ? h2 : h3;
            p0 = fmaf(W[0][i].x, hv.x, fmaf(W[0][i].y, hv.y,
                 fmaf(W[0][i].z, hv.z, fmaf(W[0][i].w, hv.w, p0))));
            p1 = fmaf(W[1][i].x, hv.x, fmaf(W[1][i].y, hv.y,
                 fmaf(W[1][i].z, hv.z, fmaf(W[1][i].w, hv.w, p1))));
            p2 = fmaf(W[2][i].x, hv.x, fmaf(W[2][i].y, hv.y,
                 fmaf(W[2][i].z, hv.z, fmaf(W[2][i].w, hv.w, p2))));
            p3 = fmaf(W[3][i].x, hv.x, fmaf(W[3][i].y, hv.y,
                 fmaf(W[3][i].z, hv.z, fmaf(W[3][i].w, hv.w, p3))));
        }

        float t01 = __shfl_xor((lg & 1) ? p0 : p1, 1);
        float s01 = ((lg & 1) ? p1 : p0) + t01;
        float t23 = __shfl_xor((lg & 1) ? p2 : p3, 1);
        float s23 = ((lg & 1) ? p3 : p2) + t23;
        float tq  = __shfl_xor((lg & 2) ? s01 : s23, 2);
        float s   = ((lg & 2) ? s23 : s01) + tq;
        s += __shfl_xor(s, 4);
        s += __shfl_xor(s, 8);
        s += __shfl_xor(s, 16);
        s += __shfl_xor(s, 32);

        float pre = s + gnow;
        float act = ((lg & 3) == 2) ? tanhf(pre) : sigmoidf_(pre);
        float a1 = __shfl(act, 1);
        float a2 = __shfl(act, 2);
        float a3 = __shfl(act, 3);

        if (lg == 0) {
            c = a1 * c + act * a2;
            float h = a3 * tanhf(c);
            csum += h;
            agent_storef(h_out + (size_t)t * HDIM + j, h);
        }
        gnow = gnext;
        // no end barrier: hbuf double-buffered; skew bounded to 1 iteration.
    }

    if (lg == 0) {
        if (c_fin)    c_fin[j]    = c;
        if (csum_out) csum_out[j] = csum;
    }
}

// ctx_bias[r] = dec_b[r] + dot(dec_Wih[r, H:2H], context)
__global__ __launch_bounds__(256)
void ctx_bias_k(const float* __restrict__ dec_Wih,
                const float* __restrict__ dec_b,
                const float* __restrict__ ctx,
                float* __restrict__ out)
{
    const int wv = threadIdx.x >> 6;
    const int lane = threadIdx.x & 63;
    const int r = blockIdx.x * 4 + wv;
    const float* wr = dec_Wih + (size_t)r * (2 * HDIM) + HDIM;
    float s = 0.f;
    for (int k = lane; k < HDIM; k += 64) s += wr[k] * ctx[k];
#pragma unroll
    for (int off = 32; off > 0; off >>= 1) s += __shfl_xor(s, off);
    if (lane == 0) out[r] = s + dec_b[r];
}

// ---------------------------------------------------------------------------
// logits_mfma (proven rounds 10-13): C = dec_h @ out_w^T + out_b, bf16x3,
// fused per-row argmax via packed u64 keys + atomicMax.
// Grid (4, 250) — x-fastest dispatch makes the 4 m-tiles sharing a B-tile
// adjacent => B-tile LLC reuse instead of 4x HBM. 512 threads, 256m x 128n.
// ---------------------------------------------------------------------------
__global__ __launch_bounds__(512, 1)
void logits_mfma(const float* __restrict__ Amat,   // dec_h (S,H)
                 const float* __restrict__ Bmat,   // out_w (V,H)
                 const float* __restrict__ bias,   // out_b (V)
                 float* __restrict__ C,            // (S,V)
                 unsigned long long* __restrict__ amax)
{
    __shared__ unsigned short Ah[256][LSTR], Al[256][LSTR];
    __shared__ unsigned short Bh[128][LSTR], Bl[128][LSTR];

    const int tid = threadIdx.x;
    const int l   = tid & 63;
    const int w   = tid >> 6;
    const int n0  = blockIdx.y * 128;   // transposed grid
    const int m0  = blockIdx.x * 256;
    const int mb  = (w >> 1) * 64;
    const int nb  = (w & 1) * 64;

    f32x4 acc[4][4];
#pragma unroll
    for (int i = 0; i < 4; ++i)
#pragma unroll
        for (int jj = 0; jj < 4; ++jj) acc[i][jj] = (f32x4){0.f, 0.f, 0.f, 0.f};

    for (int k0 = 0; k0 < HDIM; k0 += 32) {
#pragma unroll
        for (int q = 0; q < 4; ++q) {
            int id  = q * 512 + tid;
            int row = id >> 3;
            int kq  = (id & 7) * 4;
            float4 av = *(const float4*)(Amat + (size_t)(m0 + row) * HDIM
                                         + k0 + kq);
            unsigned short h0,h1,h2,h3, l0,l1,l2,l3;
            split_bf16(av.x, h0, l0); split_bf16(av.y, h1, l1);
            split_bf16(av.z, h2, l2); split_bf16(av.w, h3, l3);
            sh4 hi = {(short)h0, (short)h1, (short)h2, (short)h3};
            sh4 lo = {(short)l0, (short)l1, (short)l2, (short)l3};
            *(sh4*)&Ah[row][kq] = hi;
            *(sh4*)&Al[row][kq] = lo;
        }
#pragma unroll
        for (int q = 0; q < 2; ++q) {
            int id  = q * 512 + tid;
            int row = id >> 3;
            int kq  = (id & 7) * 4;
            float4 bv = *(const float4*)(Bmat + (size_t)(n0 + row) * HDIM
                                         + k0 + kq);
            unsigned short h0,h1,h2,h3, l0,l1,l2,l3;
            split_bf16(bv.x, h0, l0); split_bf16(bv.y, h1, l1);
            split_bf16(bv.z, h2, l2); split_bf16(bv.w, h3, l3);
            sh4 hi = {(short)h0, (short)h1, (short)h2, (short)h3};
            sh4 lo = {(short)l0, (short)l1, (short)l2, (short)l3};
            *(sh4*)&Bh[row][kq] = hi;
            *(sh4*)&Bl[row][kq] = lo;
        }
        __syncthreads();

        const int kb = (l >> 4) * 8;
        short8 a_hi[4], a_lo[4], b_hi[4], b_lo[4];
#pragma unroll
        for (int i = 0; i < 4; ++i) {
            int ra = mb + i * 16 + (l & 15);
            int rb = nb + i * 16 + (l & 15);
            a_hi[i] = *(const short8*)&Ah[ra][kb];
            a_lo[i] = *(const short8*)&Al[ra][kb];
            b_hi[i] = *(const short8*)&Bh[rb][kb];
            b_lo[i] = *(const short8*)&Bl[rb][kb];
        }
#pragma unroll
        for (int i = 0; i < 4; ++i)
#pragma unroll
            for (int jj = 0; jj < 4; ++jj) {
                acc[i][jj] = __builtin_amdgcn_mfma_f32_16x16x32_bf16(
                    a_hi[i], b_hi[jj], acc[i][jj], 0, 0, 0);
                acc[i][jj] = __builtin_amdgcn_mfma_f32_16x16x32_bf16(
                    a_hi[i], b_lo[jj], acc[i][jj], 0, 0, 0);
                acc[i][jj] = __builtin_amdgcn_mfma_f32_16x16x32_bf16(
                    a_lo[i], b_hi[jj], acc[i][jj], 0, 0, 0);
            }
        __syncthreads();
    }

    // epilogue: bias, store, fused argmax (packed monotone-float | ~col key)
#pragma unroll
    for (int i = 0; i < 4; ++i) {
        const int mrow = m0 + mb + i * 16 + ((l >> 4) << 2);
        unsigned long long key[4] = {0ull, 0ull, 0ull, 0ull};
#pragma unroll
        for (int jj = 0; jj < 4; ++jj) {
            int n = n0 + nb + jj * 16 + (l & 15);
            float bv = bias[n];
            f32x4 o = acc[i][jj];
#pragma unroll
            for (int r = 0; r < 4; ++r) {
                float val = o[r] + bv;
                C[(size_t)(mrow + r) * VDIM + n] = val;
                unsigned um = __float_as_uint(val);
                um = (um & 0x80000000u) ? ~um : (um | 0x80000000u);
                unsigned long long k2 = ((unsigned long long)um << 32)
                    | (unsigned long long)(0xFFFFFFFFu - (unsigned)n);
                if (k2 > key[r]) key[r] = k2;
            }
        }
#pragma unroll
        for (int r = 0; r < 4; ++r) {
#pragma unroll
            for (int off = 1; off < 16; off <<= 1) {
                unsigned long long other = __shfl_xor(key[r], off);
                if (other > key[r]) key[r] = other;
            }
            if ((l & 15) == 0)
                atomicMax(&amax[mrow + r], key[r]);
        }
    }
}

// decode argmax keys -> float indices
__global__ __launch_bounds__(256)
void idx_final(const unsigned long long* __restrict__ amax,
               float* __restrict__ out_idx)
{
    int i = blockIdx.x * 256 + threadIdx.x;
    if (i < S_LEN) {
        unsigned col = 0xFFFFFFFFu - (unsigned)(amax[i] & 0xFFFFFFFFull);
        out_idx[i] = (float)col;
    }
}

extern "C" void kernel_launch(void* const* d_in, const int* in_sizes, int n_in,
                              void* d_out, int out_size, void* d_ws, size_t ws_size,
                              hipStream_t stream)
{
    (void)in_sizes; (void)n_in; (void)out_size; (void)ws_size;

    const int*   input_seq = (const int*)d_in[0];
    const int*   gold_seq  = (const int*)d_in[1];
    const float* embed     = (const float*)d_in[2];
    const float* enc_Wih   = (const float*)d_in[3];
    const float* enc_Whh   = (const float*)d_in[4];
    const float* enc_b     = (const float*)d_in[5];
    const float* dec_Wih   = (const float*)d_in[6];
    const float* dec_Whh   = (const float*)d_in[7];
    const float* dec_b     = (const float*)d_in[8];
    // d_in[9..14]: attention params — dead code
    const float* out_w     = (const float*)d_in[15];
    const float* out_b     = (const float*)d_in[16];

    float* out = (float*)d_out;
    float* G_enc = out;                 // dead before logits overwrite (serial)
    float* G_dec = out + 4194304;       // dead before logits overwrite (serial)

    // workspace
    char* wsb = (char*)d_ws;
    unsigned long long* amax = (unsigned long long*)wsb;   // 8 KB
    float* zerovec = (float*)(wsb + 8192);                 // 1024 f
    float* c0      = zerovec + 1024;
    float* ctx     = c0 + 1024;
    float* ctxb    = ctx + 1024;                           // 4096 f
    float* enc_out = ctxb + 4096;                          // S*H
    float* dec_h   = enc_out + 1048576;                    // S*H

    hipMemsetAsync(d_ws, 0, 12288, stream);                // amax + zerovec
    hipMemsetAsync(enc_out, 0xFF, (size_t)S_LEN * HDIM * 4, stream);
    hipMemsetAsync(dec_h,   0xFF, (size_t)S_LEN * HDIM * 4, stream);

    // both input GEMMs, one full-chip launch (G_dec without ctxb)
    g_mfma_both<<<dim3(32, 8), 512, 0, stream>>>(
        embed, input_seq, gold_seq, enc_Wih, enc_b, dec_Wih, G_enc, G_dec);

    // encoder
    lstm_seq<<<128, 512, 0, stream>>>(
        enc_Whh, G_enc, zerovec, zerovec, enc_out, c0, ctx, S_LEN);

    // ctxb = dec_b + dec_Wih[:,H:] @ ctx
    ctx_bias_k<<<1024, 256, 0, stream>>>(dec_Wih, dec_b, ctx, ctxb);

    // G_dec += ctxb (broadcast)
    gdec_add<<<1024, 256, 0, stream>>>(G_dec, ctxb);

    // decoder — bare G loads (proven)
    lstm_seq<<<128, 512, 0, stream>>>(
        dec_Whh, G_dec, enc_out + (size_t)(S_LEN - 1) * HDIM, c0,
        dec_h, nullptr, nullptr, S_LEN);

    // logits (bf16x3 MFMA, B-tile-adjacent grid) + fused argmax
    logits_mfma<<<dim3(S_LEN / 256, VDIM / 128), 512, 0, stream>>>(
        dec_h, out_w, out_b, out, amax);

    // idxs -> d_out[S*V : S*V + S)
    idx_final<<<4, 256, 0, stream>>>(amax, out + (size_t)S_LEN * VDIM);
}